// Round 1
// baseline (481.240 us; speedup 1.0000x reference)
//
#include <hip/hip_runtime.h>
#include <hip/hip_bf16.h>

// Problem constants (from reference setup_inputs):
//   sinogram: [1, 16, 360, 736] f32   (C=16 channels, H=V=360 views, W=D=736 detectors)
//   grid:     [1, 360, 16384, 2] f32  (x,y in ~[-1.1, 1.1])
//   square_inv: [1, 1, 360, 16384] f32
//   out:      [1, 16, 16384] f32
#define NP 16384
#define NV 360
#define ND 736
#define NC 16
#define VSPLIT 16
#define CHUNK 23   // ceil(360/16)

// Pass 1: transpose sinogram [C][H*W] -> [H*W][C] so one corner's 16 channels
// are a single 64B cache line (4 aligned float4 loads).
__global__ __launch_bounds__(256) void sino_transpose(const float* __restrict__ sino,
                                                      float* __restrict__ st) {
    int idx = blockIdx.x * 256 + threadIdx.x;   // idx = y*ND + x
    if (idx >= NV * ND) return;
    float vals[NC];
#pragma unroll
    for (int c = 0; c < NC; ++c)
        vals[c] = sino[c * (NV * ND) + idx];    // coalesced per-c across threads
    float4* dst = reinterpret_cast<float4*>(st + ((size_t)idx << 4));
#pragma unroll
    for (int q = 0; q < 4; ++q)
        dst[q] = make_float4(vals[4*q], vals[4*q+1], vals[4*q+2], vals[4*q+3]);
}

// Pass 2: each thread owns (pixel p, view-chunk vs). Accumulates 16 channels
// in registers over its views, then one atomicAdd per channel.
__global__ __launch_bounds__(256) void backproj(const float* __restrict__ grd,
                                                const float* __restrict__ sq,
                                                const float* __restrict__ st,
                                                float* __restrict__ out) {
    int tid = blockIdx.x * 256 + threadIdx.x;
    int p  = tid & (NP - 1);
    int vs = tid >> 14;          // /NP
    int v0 = vs * CHUNK;
    int v1 = min(v0 + CHUNK, NV);

    float acc[NC];
#pragma unroll
    for (int c = 0; c < NC; ++c) acc[c] = 0.0f;

    const float2* grd2 = reinterpret_cast<const float2*>(grd);

    for (int v = v0; v < v1; ++v) {
        int gi = v * NP + p;
        float2 g = grd2[gi];                 // coalesced 8B/lane
        float w  = sq[gi] * 1000.0f;         // coalesced 4B/lane

        // unnormalize, align_corners=False (match reference exactly)
        float ix = ((g.x + 1.0f) * (float)ND - 1.0f) * 0.5f;
        float iy = ((g.y + 1.0f) * (float)NV - 1.0f) * 0.5f;
        float x0f = floorf(ix), y0f = floorf(iy);
        float wx = ix - x0f,   wy = iy - y0f;   // weights from UNclamped floor
        int x0i = (int)x0f, y0i = (int)y0f;
        int x0 = min(max(x0i,     0), ND - 1);
        int x1 = min(max(x0i + 1, 0), ND - 1);
        int y0 = min(max(y0i,     0), NV - 1);
        int y1 = min(max(y0i + 1, 0), NV - 1);

        float w00 = (1.0f - wx) * (1.0f - wy) * w;
        float w01 = wx * (1.0f - wy) * w;
        float w10 = (1.0f - wx) * wy * w;
        float w11 = wx * wy * w;

        const float4* c00 = reinterpret_cast<const float4*>(st + ((y0 * ND + x0) << 4));
        const float4* c01 = reinterpret_cast<const float4*>(st + ((y0 * ND + x1) << 4));
        const float4* c10 = reinterpret_cast<const float4*>(st + ((y1 * ND + x0) << 4));
        const float4* c11 = reinterpret_cast<const float4*>(st + ((y1 * ND + x1) << 4));

#pragma unroll
        for (int q = 0; q < 4; ++q) {
            float4 a = c00[q], b = c01[q], cc = c10[q], d = c11[q];
            acc[4*q+0] += a.x * w00 + b.x * w01 + cc.x * w10 + d.x * w11;
            acc[4*q+1] += a.y * w00 + b.y * w01 + cc.y * w10 + d.y * w11;
            acc[4*q+2] += a.z * w00 + b.z * w01 + cc.z * w10 + d.z * w11;
            acc[4*q+3] += a.w * w00 + b.w * w01 + cc.w * w10 + d.w * w11;
        }
    }

#pragma unroll
    for (int c = 0; c < NC; ++c)
        atomicAdd(&out[c * NP + p], acc[c]);   // 16 contenders per location
}

extern "C" void kernel_launch(void* const* d_in, const int* in_sizes, int n_in,
                              void* d_out, int out_size, void* d_ws, size_t ws_size,
                              hipStream_t stream) {
    const float* sino = (const float*)d_in[0];
    const float* grd  = (const float*)d_in[1];
    const float* sq   = (const float*)d_in[2];
    float* out = (float*)d_out;
    float* st  = (float*)d_ws;            // needs NV*ND*NC*4 = ~17 MB

    // out is poisoned 0xAA before every launch; we accumulate with atomics.
    hipMemsetAsync(out, 0, (size_t)out_size * sizeof(float), stream);

    {
        int n = NV * ND;
        sino_transpose<<<(n + 255) / 256, 256, 0, stream>>>(sino, st);
    }
    {
        int nthreads = NP * VSPLIT;
        backproj<<<nthreads / 256, 256, 0, stream>>>(grd, sq, st, out);
    }
}

// Round 2
// 273.830 us; speedup vs baseline: 1.7574x; 1.7574x over previous
//
#include <hip/hip_runtime.h>
#include <hip/hip_bf16.h>

// sinogram: [1,16,360,736] f32, grid: [1,360,16384,2] f32,
// square_inv: [1,1,360,16384] f32, out: [1,16,16384] f32
#define NP 16384
#define NV 360
#define ND 736
#define NC 16
#define VSPLIT 32

// Pass 1: transpose + quantize sinogram [C][H*W] -> bf16 [H*W][C].
// One corner's 16 channels = 32 contiguous bytes; x-adjacent corners share a
// 64B line. Table shrinks 17MB -> 8.5MB (better per-XCD L2 residency).
__global__ __launch_bounds__(256) void sino_transpose_bf16(const float* __restrict__ sino,
                                                           ushort* __restrict__ st) {
    int idx = blockIdx.x * 256 + threadIdx.x;   // idx = y*ND + x
    if (idx >= NV * ND) return;
    uint packed[8];
#pragma unroll
    for (int q = 0; q < 8; ++q) {
        uint ul = __float_as_uint(sino[(2 * q)     * (NV * ND) + idx]);
        uint uh = __float_as_uint(sino[(2 * q + 1) * (NV * ND) + idx]);
        // round-to-nearest-even bf16
        ul = (ul + 0x7fffu + ((ul >> 16) & 1u)) >> 16;
        uh = (uh + 0x7fffu + ((uh >> 16) & 1u)) >> 16;
        packed[q] = ul | (uh << 16);
    }
    uint4* dst = reinterpret_cast<uint4*>(st + ((size_t)idx << 4));
    dst[0] = make_uint4(packed[0], packed[1], packed[2], packed[3]);
    dst[1] = make_uint4(packed[4], packed[5], packed[6], packed[7]);
}

// Pass 2: thread = (pixel p, view-chunk vs); 16 fp32 accumulators in regs,
// one atomicAdd per channel at the end. 8192 waves -> 32 waves/CU.
__global__ __launch_bounds__(256) void backproj(const float* __restrict__ grd,
                                                const float* __restrict__ sq,
                                                const ushort* __restrict__ st,
                                                float* __restrict__ out) {
    int tid = blockIdx.x * 256 + threadIdx.x;
    int p  = tid & (NP - 1);
    int vs = tid >> 14;                  // /NP
    int v0 = (vs * NV) / VSPLIT;         // balanced 11/12-view chunks
    int v1 = ((vs + 1) * NV) / VSPLIT;

    float acc[NC];
#pragma unroll
    for (int c = 0; c < NC; ++c) acc[c] = 0.0f;

    const float2* grd2 = reinterpret_cast<const float2*>(grd);

    auto gather = [&](int idx, float w) {
        const uint4* pp = reinterpret_cast<const uint4*>(st + ((size_t)idx << 4));
        uint4 a = pp[0], b = pp[1];
        uint u[8] = {a.x, a.y, a.z, a.w, b.x, b.y, b.z, b.w};
#pragma unroll
        for (int q = 0; q < 8; ++q) {
            acc[2 * q]     = fmaf(__uint_as_float(u[q] << 16),         w, acc[2 * q]);
            acc[2 * q + 1] = fmaf(__uint_as_float(u[q] & 0xffff0000u), w, acc[2 * q + 1]);
        }
    };

    for (int v = v0; v < v1; ++v) {
        int gi = v * NP + p;
        float2 g = grd2[gi];                 // coalesced 8B/lane
        float w  = sq[gi] * 1000.0f;         // coalesced 4B/lane

        float ix = ((g.x + 1.0f) * (float)ND - 1.0f) * 0.5f;
        float iy = ((g.y + 1.0f) * (float)NV - 1.0f) * 0.5f;
        float x0f = floorf(ix), y0f = floorf(iy);
        float wx = ix - x0f,   wy = iy - y0f;    // weights from UNclamped floor
        int x0i = (int)x0f, y0i = (int)y0f;
        int x0 = min(max(x0i,     0), ND - 1);
        int x1 = min(max(x0i + 1, 0), ND - 1);
        int y0 = min(max(y0i,     0), NV - 1);
        int y1 = min(max(y0i + 1, 0), NV - 1);

        float w00 = (1.0f - wx) * (1.0f - wy) * w;
        float w01 = wx * (1.0f - wy) * w;
        float w10 = (1.0f - wx) * wy * w;
        float w11 = wx * wy * w;

        gather(y0 * ND + x0, w00);
        gather(y0 * ND + x1, w01);
        gather(y1 * ND + x0, w10);
        gather(y1 * ND + x1, w11);
    }

#pragma unroll
    for (int c = 0; c < NC; ++c)
        atomicAdd(&out[c * NP + p], acc[c]);   // 32 contenders per location
}

extern "C" void kernel_launch(void* const* d_in, const int* in_sizes, int n_in,
                              void* d_out, int out_size, void* d_ws, size_t ws_size,
                              hipStream_t stream) {
    const float* sino = (const float*)d_in[0];
    const float* grd  = (const float*)d_in[1];
    const float* sq   = (const float*)d_in[2];
    float* out = (float*)d_out;
    ushort* st = (ushort*)d_ws;           // NV*ND*NC*2 = 8.5 MB

    hipMemsetAsync(out, 0, (size_t)out_size * sizeof(float), stream);

    {
        int n = NV * ND;
        sino_transpose_bf16<<<(n + 255) / 256, 256, 0, stream>>>(sino, st);
    }
    {
        int nthreads = NP * VSPLIT;       // 524288
        backproj<<<nthreads / 256, 256, 0, stream>>>(grd, sq, st, out);
    }
}